// Round 4
// baseline (192.980 us; speedup 1.0000x reference)
//
#include <hip/hip_runtime.h>
#include <math.h>

// DigitCaps routing, single fused kernel. Grid=128 (one block per batch
// element), 1024 threads = 16 waves = 4 waves/SIMD for latency hiding.
// R3 failed because per-thread wv[80]+tl[80] spilled at the 1024-thread
// VGPR cap (VGPR=64, 282 MB scratch traffic). Fix: o-dimension split across
// thread PAIRS -> per-thread wv[5][8]+tl[5][8] (~108 VGPR < 128 cap),
// softmax halves stitched with __shfl_xor(...,1).
//
// Mapping: tid = c(5b) | slot(4b) | h(1b).  c=channel, slot=hw-slot (9 hw
// each), h=o-half (h=0 -> o 0..4, h=1 -> o 5..9).
//
// Algebra (u_hat never materialized):
//   t0[c,o,q]   = 0.1 * sum_hw u[c,hw,q]
//   v           = squash( s[o,p] = sum_{c,q} Wm[c,o,p,q] * t[c,o,q] )
//   logits      = u . wv,  wv[c,o,q] = sum_p Wm[c,o,p,q] * vacc[o,p],
//                 vacc = v1 (+ v2)   (b_ij accumulation is linear in v)

#define CC 32
#define HWN 144
#define QQ 8
#define OO 10
#define PP 16
#define EE 80    // OO*QQ
#define NT 1024

__device__ __forceinline__ float compute_v(const float* __restrict__ Wm,
                                           const float* t_s, int tid) {
    // tid < 160 only. o = tid>>4, p = tid&15.
    const int o = tid >> 4, p = tid & 15;
    float s = 0.f;
#pragma unroll 8
    for (int cc = 0; cc < CC; ++cc) {
        const float4* w4 = (const float4*)(Wm + (((cc * OO + o) * PP + p) * QQ));
        const float4* t4 = (const float4*)(t_s + cc * EE + o * QQ);
        float4 w0 = w4[0], w1 = w4[1];
        float4 t0 = t4[0], t1 = t4[1];
        s += w0.x * t0.x + w0.y * t0.y + w0.z * t0.z + w0.w * t0.w
           + w1.x * t1.x + w1.y * t1.y + w1.z * t1.z + w1.w * t1.w;
    }
    float sn = s * s;
#pragma unroll
    for (int m = 1; m <= 8; m <<= 1) sn += __shfl_xor(sn, m);  // over p-group
    return s * (sqrtf(sn) / (1.f + sn));
}

__global__ __launch_bounds__(NT, 4)   // 4 waves/EU -> <=128 VGPR
void digitcaps_fused(const float* __restrict__ x, const float* __restrict__ Wm,
                     float* __restrict__ out) {
    const int b    = blockIdx.x;
    const int tid  = threadIdx.x;
    const int c    = tid >> 5;          // 0..31
    const int h    = tid & 1;           // o-half: 0 -> o0..4, 1 -> o5..9
    const int slot = (tid >> 1) & 15;   // 0..15, 9 hw each

    __shared__ float usum_s[CC * QQ];   // 1 KB
    __shared__ float t_s[CC * EE];      // 10 KB
    __shared__ float wv_s[CC * EE];     // 10 KB
    __shared__ float vacc_s[OO * PP];   // 640 B

    const float* xc = x + ((size_t)(b * CC + c)) * (HWN * QQ);

    // ---- Phase A: usum[c][q] = sum_hw x[b,c,hw,q] ----
    {
        const int s32 = tid & 31;
        float us[QQ];
#pragma unroll
        for (int q = 0; q < QQ; ++q) us[q] = 0.f;
#pragma unroll
        for (int i = 0; i < 4; ++i) {
            const float4* p4 = (const float4*)(xc + (s32 + (i << 5)) * QQ);
            float4 a = p4[0], d = p4[1];
            us[0] += a.x; us[1] += a.y; us[2] += a.z; us[3] += a.w;
            us[4] += d.x; us[5] += d.y; us[6] += d.z; us[7] += d.w;
        }
        if (s32 < 16) {
            const float4* p4 = (const float4*)(xc + (128 + s32) * QQ);
            float4 a = p4[0], d = p4[1];
            us[0] += a.x; us[1] += a.y; us[2] += a.z; us[3] += a.w;
            us[4] += d.x; us[5] += d.y; us[6] += d.z; us[7] += d.w;
        }
#pragma unroll
        for (int m = 1; m <= 16; m <<= 1) {
#pragma unroll
            for (int q = 0; q < QQ; ++q) us[q] += __shfl_xor(us[q], m);
        }
        if (s32 == 0) {
            float4* dst = (float4*)&usum_s[c * QQ];
            dst[0] = make_float4(us[0], us[1], us[2], us[3]);
            dst[1] = make_float4(us[4], us[5], us[6], us[7]);
        }
    }
    __syncthreads();

    // t0 = 0.1 * usum, broadcast over o
    for (int k = tid; k < CC * EE; k += NT)
        t_s[k] = 0.1f * usum_s[(k / EE) * QQ + (k & 7)];
    __syncthreads();

    // v1
    if (tid < OO * PP) vacc_s[tid] = compute_v(Wm, t_s, tid);
    __syncthreads();

    for (int it = 0; it < 2; ++it) {
        // ---- C1: wv[c,o,q] = sum_p Wm[c,o,p,q] * vacc[o,p] ----
        for (int k = tid; k < CC * EE; k += NT) {
            const int cc = k / EE, rem = k - cc * EE;
            const int o = rem >> 3, q = rem & 7;
            const float* wp = Wm + ((size_t)(cc * OO + o) * PP) * QQ + q;
            float acc = 0.f;
#pragma unroll
            for (int p = 0; p < PP; ++p) acc += wp[p * QQ] * vacc_s[o * PP + p];
            wv_s[k] = acc;
        }
        __syncthreads();

        // ---- C2: logits/softmax/t, o split across thread pairs ----
        float wv[5][QQ];   // my 5 o's
        {
            const float4* src = (const float4*)(wv_s + c * EE + h * 40);
#pragma unroll
            for (int j = 0; j < 5; ++j) {
                float4 w0 = src[2 * j], w1 = src[2 * j + 1];
                wv[j][0] = w0.x; wv[j][1] = w0.y; wv[j][2] = w0.z; wv[j][3] = w0.w;
                wv[j][4] = w1.x; wv[j][5] = w1.y; wv[j][6] = w1.z; wv[j][7] = w1.w;
            }
        }
        float tl[5][QQ];
#pragma unroll
        for (int j = 0; j < 5; ++j)
#pragma unroll
            for (int q = 0; q < QQ; ++q) tl[j][q] = 0.f;

#pragma unroll
        for (int i = 0; i < 9; ++i) {
            const int hw = slot + (i << 4);
            const float4* p4 = (const float4*)(xc + hw * QQ);
            float4 a = p4[0], d = p4[1];
            float u[QQ] = {a.x, a.y, a.z, a.w, d.x, d.y, d.z, d.w};
            float lg[5];
#pragma unroll
            for (int j = 0; j < 5; ++j) {
                float s = 0.f;
#pragma unroll
                for (int q = 0; q < QQ; ++q) s += u[q] * wv[j][q];
                lg[j] = s;
            }
            // stitch softmax across the pair
            float mx = lg[0];
#pragma unroll
            for (int j = 1; j < 5; ++j) mx = fmaxf(mx, lg[j]);
#pragma unroll
            for (int j = 0; j < 5; ++j) mx = fmaxf(mx, __shfl_xor(lg[j], 1));
            float e[5], ssum = 0.f;
#pragma unroll
            for (int j = 0; j < 5; ++j) { e[j] = __expf(lg[j] - mx); ssum += e[j]; }
            const float stot = ssum + __shfl_xor(ssum, 1);
            const float inv = __builtin_amdgcn_rcpf(stot);
#pragma unroll
            for (int j = 0; j < 5; ++j) {
                const float cij = e[j] * inv;
#pragma unroll
                for (int q = 0; q < QQ; ++q) tl[j][q] += cij * u[q];
            }
        }

        // reduce over the 16 slots (tid bits 1..4)
#pragma unroll
        for (int m = 2; m <= 16; m <<= 1) {
#pragma unroll
            for (int j = 0; j < 5; ++j)
#pragma unroll
                for (int q = 0; q < QQ; ++q) tl[j][q] += __shfl_xor(tl[j][q], m);
        }
        if (slot == 0) {
            float4* dst = (float4*)&t_s[c * EE + h * 40];
#pragma unroll
            for (int j = 0; j < 5; ++j) {
                dst[2 * j]     = make_float4(tl[j][0], tl[j][1], tl[j][2], tl[j][3]);
                dst[2 * j + 1] = make_float4(tl[j][4], tl[j][5], tl[j][6], tl[j][7]);
            }
        }
        __syncthreads();

        // ---- v = squash(Wm . t) ----
        if (tid < OO * PP) {
            float v = compute_v(Wm, t_s, tid);
            if (it == 0) vacc_s[tid] += v;
            else         out[(size_t)b * (OO * PP) + tid] = v;
        }
        __syncthreads();
    }
}

extern "C" void kernel_launch(void* const* d_in, const int* in_sizes, int n_in,
                              void* d_out, int out_size, void* d_ws, size_t ws_size,
                              hipStream_t stream) {
    const float* x  = (const float*)d_in[0];   // [128,32,12,12,8]
    const float* Wm = (const float*)d_in[1];   // [32,10,16,8]
    float* out = (float*)d_out;                // [128,10,16]
    digitcaps_fused<<<128, NT, 0, stream>>>(x, Wm, out);
}

// Round 5
// 114.473 us; speedup vs baseline: 1.6858x; 1.6858x over previous
//
#include <hip/hip_runtime.h>
#include <math.h>

// DigitCaps routing, 4-kernel chain.
// Lessons: R3/R4 -> 1024-thr blocks cap VGPR at 64 and spill (282/241 MB
// scratch traffic). R1 -> 256-thr blocks get 160 VGPR, no spill, but grid=128
// left half the chip idle at 1 wave/SIMD (VALUBusy 12.5%).
// This version: heavy kernel at grid=512 (b x 4 channel-groups) x 256 thr,
// per-thread state ~110 VGPR via o-split across lane pairs (xor-16 stitch).
// Per-b coupling (t -> v) solved by computing the tiny v REDUNDANTLY in every
// block (160 thr x 256 FMA) instead of any cross-block sync.
//
// Algebra (u_hat never materialized):
//   usum[b,c,q] = sum_hw x[b,c,hw,q]
//   v1 = squash(0.1 * Wm . usum)                     (iter-1 uniform softmax)
//   wv[c,o,q] = sum_p Wm[c,o,p,q] * vacc[o,p],  vacc = v1 (+ v2)  (linear)
//   logits[n,o] = u . wv ; c_ij = softmax_o ; t[c,o,q] = sum_hw c_ij * u
//   v_{k+1} = squash(Wm . t)

#define CC 32
#define HWN 144
#define QQ 8
#define OO 10
#define PP 16
#define EE 80   // OO*QQ

// ---- K1: usum[b,c,q] = sum_hw x.  grid B*C=4096, block 64. HBM-bound. ----
__global__ __launch_bounds__(64)
void k_usum(const float* __restrict__ x, float* __restrict__ usum) {
    const int blk = blockIdx.x;           // b*32 + c
    const int l   = threadIdx.x;
    const float* xc = x + (size_t)blk * (HWN * QQ);
    float us[QQ];
#pragma unroll
    for (int q = 0; q < QQ; ++q) us[q] = 0.f;
#pragma unroll
    for (int i = 0; i < 2; ++i) {
        const float4* p4 = (const float4*)(xc + (l + (i << 6)) * QQ);
        float4 a = p4[0], d = p4[1];
        us[0] += a.x; us[1] += a.y; us[2] += a.z; us[3] += a.w;
        us[4] += d.x; us[5] += d.y; us[6] += d.z; us[7] += d.w;
    }
    if (l < 16) {
        const float4* p4 = (const float4*)(xc + (128 + l) * QQ);
        float4 a = p4[0], d = p4[1];
        us[0] += a.x; us[1] += a.y; us[2] += a.z; us[3] += a.w;
        us[4] += d.x; us[5] += d.y; us[6] += d.z; us[7] += d.w;
    }
#pragma unroll
    for (int m = 1; m <= 32; m <<= 1) {
#pragma unroll
        for (int q = 0; q < QQ; ++q) us[q] += __shfl_xor(us[q], m);
    }
    if (l == 0) {
        float4* dst = (float4*)(usum + (size_t)blk * QQ);
        dst[0] = make_float4(us[0], us[1], us[2], us[3]);
        dst[1] = make_float4(us[4], us[5], us[6], us[7]);
    }
}

// ---- K2/K3: routing iteration. grid = B*4 = 512, block 256. ----
// Block handles (b, channel-group of 8). v is recomputed redundantly.
// have_t = 0: vacc = v1(usum).  have_t = 1: vacc = v1(usum) + v2(t_in).
__global__ __launch_bounds__(256)
void k_route(const float* __restrict__ x, const float* __restrict__ Wm,
             const float* __restrict__ usum, const float* __restrict__ t_in,
             float* __restrict__ t_out, int have_t) {
    const int b   = blockIdx.x >> 2;
    const int cg  = blockIdx.x & 3;
    const int tid = threadIdx.x;
    const int cl  = tid >> 5;           // 0..7 local channel
    const int c   = (cg << 3) + cl;
    const int lane32 = tid & 31;
    const int slot   = lane32 & 15;     // hw-slot, 9 hw each
    const int h      = lane32 >> 4;     // o-half: 0 -> o0..4, 1 -> o5..9

    __shared__ float usum_s[CC * QQ];   // 1 KB
    __shared__ float tin_s[CC * EE];    // 10 KB
    __shared__ float vacc_s[OO * PP];   // 640 B
    __shared__ float wv_s[8 * EE];      // 2.5 KB

    if (tid < CC * QQ) usum_s[tid] = usum[(size_t)b * CC * QQ + tid];
    if (have_t) {
        for (int k = tid; k < CC * EE; k += 256)
            tin_s[k] = t_in[(size_t)b * CC * EE + k];
    }
    __syncthreads();

    // ---- redundant v: vacc[o,p] ----
    if (tid < OO * PP) {
        const int o = tid >> 4, p = tid & 15;
        float s1 = 0.f, s2 = 0.f;
#pragma unroll 8
        for (int cc = 0; cc < CC; ++cc) {
            const float4* w4 = (const float4*)(Wm + (((cc * OO + o) * PP + p) * QQ));
            float4 w0 = w4[0], w1 = w4[1];
            const float* uq = &usum_s[cc * QQ];
            s1 += w0.x * uq[0] + w0.y * uq[1] + w0.z * uq[2] + w0.w * uq[3]
                + w1.x * uq[4] + w1.y * uq[5] + w1.z * uq[6] + w1.w * uq[7];
            if (have_t) {
                const float* tq = &tin_s[cc * EE + o * QQ];
                s2 += w0.x * tq[0] + w0.y * tq[1] + w0.z * tq[2] + w0.w * tq[3]
                    + w1.x * tq[4] + w1.y * tq[5] + w1.z * tq[6] + w1.w * tq[7];
            }
        }
        s1 *= 0.1f;
        float sn1 = s1 * s1;
#pragma unroll
        for (int m = 1; m <= 8; m <<= 1) sn1 += __shfl_xor(sn1, m);
        float v = s1 * (sqrtf(sn1) / (1.f + sn1));
        if (have_t) {
            float sn2 = s2 * s2;
#pragma unroll
            for (int m = 1; m <= 8; m <<= 1) sn2 += __shfl_xor(sn2, m);
            v += s2 * (sqrtf(sn2) / (1.f + sn2));
        }
        vacc_s[tid] = v;
    }
    __syncthreads();

    // ---- wv[cl,o,q] = sum_p Wm[c,o,p,q] * vacc[o,p] for my 8 channels ----
    for (int k = tid; k < 8 * EE; k += 256) {
        const int ccl = k / EE, rem = k - ccl * EE;
        const int o = rem >> 3, q = rem & 7;
        const float* wp = Wm + ((size_t)(((cg << 3) + ccl) * OO + o) * PP) * QQ + q;
        float acc = 0.f;
#pragma unroll
        for (int p = 0; p < PP; ++p) acc += wp[p * QQ] * vacc_s[o * PP + p];
        wv_s[k] = acc;
    }
    __syncthreads();

    // ---- C2: logits / softmax / t for my channel, my 5 o's, my 9 hw ----
    float wv[5][QQ];
    {
        const float4* src = (const float4*)(wv_s + cl * EE + h * 40);
#pragma unroll
        for (int j = 0; j < 5; ++j) {
            float4 w0 = src[2 * j], w1 = src[2 * j + 1];
            wv[j][0] = w0.x; wv[j][1] = w0.y; wv[j][2] = w0.z; wv[j][3] = w0.w;
            wv[j][4] = w1.x; wv[j][5] = w1.y; wv[j][6] = w1.z; wv[j][7] = w1.w;
        }
    }
    float tl[5][QQ];
#pragma unroll
    for (int j = 0; j < 5; ++j)
#pragma unroll
        for (int q = 0; q < QQ; ++q) tl[j][q] = 0.f;

    const float* xc = x + ((size_t)(b * CC + c)) * (HWN * QQ);
#pragma unroll
    for (int i = 0; i < 9; ++i) {
        const int hw = slot + (i << 4);
        const float4* p4 = (const float4*)(xc + hw * QQ);
        float4 a = p4[0], d = p4[1];
        float u[QQ] = {a.x, a.y, a.z, a.w, d.x, d.y, d.z, d.w};
        float lg[5];
#pragma unroll
        for (int j = 0; j < 5; ++j) {
            float s = 0.f;
#pragma unroll
            for (int q = 0; q < QQ; ++q) s += u[q] * wv[j][q];
            lg[j] = s;
        }
        float mx = lg[0];
#pragma unroll
        for (int j = 1; j < 5; ++j) mx = fmaxf(mx, lg[j]);
#pragma unroll
        for (int j = 0; j < 5; ++j) mx = fmaxf(mx, __shfl_xor(lg[j], 16));
        float e[5], ssum = 0.f;
#pragma unroll
        for (int j = 0; j < 5; ++j) { e[j] = __expf(lg[j] - mx); ssum += e[j]; }
        const float stot = ssum + __shfl_xor(ssum, 16);
        const float inv = 1.f / stot;
#pragma unroll
        for (int j = 0; j < 5; ++j) {
            const float cij = e[j] * inv;
#pragma unroll
            for (int q = 0; q < QQ; ++q) tl[j][q] += cij * u[q];
        }
    }

    // reduce over the 16 slots (lane bits 0..3)
#pragma unroll
    for (int m = 1; m <= 8; m <<= 1) {
#pragma unroll
        for (int j = 0; j < 5; ++j)
#pragma unroll
            for (int q = 0; q < QQ; ++q) tl[j][q] += __shfl_xor(tl[j][q], m);
    }
    if (slot == 0) {
        float4* dst = (float4*)(t_out + ((size_t)(b * CC + c)) * EE + h * 40);
#pragma unroll
        for (int j = 0; j < 5; ++j) {
            dst[2 * j]     = make_float4(tl[j][0], tl[j][1], tl[j][2], tl[j][3]);
            dst[2 * j + 1] = make_float4(tl[j][4], tl[j][5], tl[j][6], tl[j][7]);
        }
    }
}

// ---- K4: v3 = squash(Wm . t2) -> out. grid B=128, block 192 (160 active). ----
__global__ __launch_bounds__(192)
void k_v(const float* __restrict__ Wm, const float* __restrict__ t,
         float* __restrict__ v) {
    const int b = blockIdx.x, tid = threadIdx.x;
    if (tid >= OO * PP) return;
    const int o = tid >> 4, p = tid & 15;
    float s = 0.f;
#pragma unroll 8
    for (int cc = 0; cc < CC; ++cc) {
        const float4* w4 = (const float4*)(Wm + (((cc * OO + o) * PP + p) * QQ));
        const float4* t4 = (const float4*)(t + ((size_t)(b * CC + cc)) * EE + o * QQ);
        float4 w0 = w4[0], w1 = w4[1];
        float4 t0 = t4[0], t1 = t4[1];
        s += w0.x * t0.x + w0.y * t0.y + w0.z * t0.z + w0.w * t0.w
           + w1.x * t1.x + w1.y * t1.y + w1.z * t1.z + w1.w * t1.w;
    }
    float sn = s * s;
#pragma unroll
    for (int m = 1; m <= 8; m <<= 1) sn += __shfl_xor(sn, m);
    v[b * (OO * PP) + tid] = s * (sqrtf(sn) / (1.f + sn));
}

extern "C" void kernel_launch(void* const* d_in, const int* in_sizes, int n_in,
                              void* d_out, int out_size, void* d_ws, size_t ws_size,
                              hipStream_t stream) {
    const float* x  = (const float*)d_in[0];   // [128,32,12,12,8]
    const float* Wm = (const float*)d_in[1];   // [32,10,16,8]
    float* out = (float*)d_out;                // [128,10,16]

    float* usum = (float*)d_ws;                // 4096*8   = 32768 f
    float* t1   = usum + 4096 * QQ;            // 4096*80  = 327680 f
    float* t2   = t1 + 4096 * EE;              // 4096*80  (total ~2.8 MB)

    k_usum <<<4096, 64, 0, stream>>>(x, usum);
    k_route<<<512, 256, 0, stream>>>(x, Wm, usum, t1, t1, 0);
    k_route<<<512, 256, 0, stream>>>(x, Wm, usum, t1, t2, 1);
    k_v    <<<128, 192, 0, stream>>>(Wm, t2, out);
}